// Round 13
// baseline (118.299 us; speedup 1.0000x reference)
//
#include <hip/hip_runtime.h>

// x (B,I); w/s/t (O,I); out (B,O), all fp32.
#define B_SZ 256
#define O_SZ 1024
#define I_SZ 1024

#define TB   4     // b rows per block (LDS x tile)
#define SLN  32    // lanes per half splitting i
#define KITERS (I_SZ / (SLN * 4))   // 8
#define ISTEP  (SLN * 4)            // 128
#define OITER  4                    // o-groups per block (32 o's/block)
#define OSTRIDE (8 * I_SZ)          // element stride between o-groups

typedef float v2f __attribute__((ext_vector_type(2)));

// out[b,o] = sum_i w[o,i]*phi((x[b,i]-t[o,i])/s[o,i]),  phi(z) = -z*exp(-0.5 z^2)
// u = K*(x-t)/s, K = sqrt(0.5*log2 e) -> exp2(-u^2) = exp(-z^2/2);  w*z = u*(w/K)
// fma/mul packed (v_pk_*_f32); exp2 on trans pipe (~16 cyc/wave).
//
// R12 post-mortem: doubling occupancy (4->8 waves/SIMD) did NOT lift duty (61->66%)
// -- the stall is CORRELATED across waves: w/s/t prefetch distance 1 gives only
// ~160 cyc of compute cover vs ~250-400 cyc warm-L2 latency (w/s/t re-read 64x by
// y-blocks, ~13 TB/s L2 load). Every wave stalls on vmcnt every k-iter.
// This round: prefetch depth 2 (A/B register buffer sets, consume g / prefetch g+2),
// linear step g = oi*8+k with modular goff() so the stream crosses oi boundaries.
// Body = R12's proven 32-VGPR structure; +12 VGPR for the second buffer fits the
// 64-cap of (256,8). Spill watch: WRITE_SIZE ~1.4 MB.
__device__ __forceinline__ int goff(int g) {
    g &= (8 * OITER - 1);                       // mod 32
    return (g >> 3) * OSTRIDE + (g & 7) * ISTEP;
}

__launch_bounds__(256, 8)
__global__ void wavkan_dog_kernel(const float* __restrict__ X,
                                  const float* __restrict__ W,
                                  const float* __restrict__ S,
                                  const float* __restrict__ T,
                                  float* __restrict__ Out) {
    const int tid  = threadIdx.x;
    const int wave = tid >> 6;
    const int lane = tid & 63;
    const int half = lane >> 5;
    const int sl   = lane & (SLN - 1);

    const int obase = blockIdx.x * (8 * OITER) + wave * 2 + half; // + oi*8
    const int b0    = blockIdx.y * TB;

    __shared__ __align__(16) float xls[TB * I_SZ];     // 16 KB

    const int r0 = obase * I_SZ + sl * 4;
    const float* wr = W + r0;
    const float* sr = S + r0;
    const float* tr = T + r0;

    // depth-2 prefetch: preload steps g=0 (A) and g=1 (B) before the LDS fill
    float4 sA = *(const float4*)(sr);
    float4 tA = *(const float4*)(tr);
    float4 wA = *(const float4*)(wr);
    float4 sB = *(const float4*)(sr + ISTEP);
    float4 tB = *(const float4*)(tr + ISTEP);
    float4 wB = *(const float4*)(wr + ISTEP);

    {   // cooperative fill: x[b0:b0+4][:] is one contiguous 16 KB span
        const float4* Xg4 = (const float4*)(X + (size_t)b0 * I_SZ);
        float4* L4 = (float4*)xls;
#pragma unroll
        for (int p = 0; p < (TB * I_SZ / 4) / 256; ++p)
            L4[tid + p * 256] = Xg4[tid + p * 256];
    }
    __syncthreads();

    const float K  = 0.84932180028801904272f;  // sqrt(0.5 * log2 e)
    const float iK = 1.17741002251547469101f;  // 1/K
    const float* xb = xls + sl * 4;

#pragma unroll 1
    for (int oi = 0; oi < OITER; ++oi) {
        v2f acc[TB];
#pragma unroll
        for (int j = 0; j < TB; ++j) acc[j] = (v2f)(0.0f);

#pragma unroll 1
        for (int k = 0; k < KITERS; k += 2) {
            const int g = oi * 8 + k;

            // ---- phase A: consume buffer A (step g), prefetch step g+2 into A
            {
                const float4 s4 = sA, t4 = tA, w4 = wA;
                const int pf = goff(g + 2);
                sA = *(const float4*)(sr + pf);
                tA = *(const float4*)(tr + pf);
                wA = *(const float4*)(wr + pf);

                v2f rk[2], tkn[2], wk[2];
                const float* sa = (const float*)&s4;
                const float* ta = (const float*)&t4;
                const float* wa = (const float*)&w4;
#pragma unroll
                for (int cp = 0; cp < 2; ++cp) {
                    const v2f r  = { __builtin_amdgcn_rcpf(sa[2*cp]),
                                     __builtin_amdgcn_rcpf(sa[2*cp+1]) };
                    const v2f tt = { ta[2*cp], ta[2*cp+1] };
                    const v2f ww = { wa[2*cp], wa[2*cp+1] };
                    rk[cp]  = r * K;
                    tkn[cp] = -(tt * rk[cp]);
                    wk[cp]  = ww * iK;
                }
                const int i = k * ISTEP;
#pragma unroll
                for (int j = 0; j < TB; ++j) {
                    const float4 xv = *(const float4*)(xb + j * I_SZ + i);
                    const float* xp = (const float*)&xv;
#pragma unroll
                    for (int cp = 0; cp < 2; ++cp) {
                        const v2f x2 = { xp[2*cp], xp[2*cp+1] };
                        const v2f u  = __builtin_elementwise_fma(x2, rk[cp], tkn[cp]);
                        const v2f m  = u * (-u);
                        v2f e;
                        e.x = __builtin_amdgcn_exp2f(m.x);
                        e.y = __builtin_amdgcn_exp2f(m.y);
                        const v2f y = u * wk[cp];
                        acc[j] = __builtin_elementwise_fma(-y, e, acc[j]);
                    }
                }
            }

            // ---- phase B: consume buffer B (step g+1), prefetch step g+3 into B
            {
                const float4 s4 = sB, t4 = tB, w4 = wB;
                const int pf = goff(g + 3);
                sB = *(const float4*)(sr + pf);
                tB = *(const float4*)(tr + pf);
                wB = *(const float4*)(wr + pf);

                v2f rk[2], tkn[2], wk[2];
                const float* sa = (const float*)&s4;
                const float* ta = (const float*)&t4;
                const float* wa = (const float*)&w4;
#pragma unroll
                for (int cp = 0; cp < 2; ++cp) {
                    const v2f r  = { __builtin_amdgcn_rcpf(sa[2*cp]),
                                     __builtin_amdgcn_rcpf(sa[2*cp+1]) };
                    const v2f tt = { ta[2*cp], ta[2*cp+1] };
                    const v2f ww = { wa[2*cp], wa[2*cp+1] };
                    rk[cp]  = r * K;
                    tkn[cp] = -(tt * rk[cp]);
                    wk[cp]  = ww * iK;
                }
                const int i = (k + 1) * ISTEP;
#pragma unroll
                for (int j = 0; j < TB; ++j) {
                    const float4 xv = *(const float4*)(xb + j * I_SZ + i);
                    const float* xp = (const float*)&xv;
#pragma unroll
                    for (int cp = 0; cp < 2; ++cp) {
                        const v2f x2 = { xp[2*cp], xp[2*cp+1] };
                        const v2f u  = __builtin_elementwise_fma(x2, rk[cp], tkn[cp]);
                        const v2f m  = u * (-u);
                        v2f e;
                        e.x = __builtin_amdgcn_exp2f(m.x);
                        e.y = __builtin_amdgcn_exp2f(m.y);
                        const v2f y = u * wk[cp];
                        acc[j] = __builtin_elementwise_fma(-y, e, acc[j]);
                    }
                }
            }
        }

        // collapse pairs, reduce across the 32 i-split lanes
        float r[TB];
#pragma unroll
        for (int j = 0; j < TB; ++j) r[j] = acc[j].x + acc[j].y;
#pragma unroll
        for (int m = 1; m < SLN; m <<= 1)
#pragma unroll
            for (int j = 0; j < TB; ++j)
                r[j] += __shfl_xor(r[j], m, 64);

        if (sl < TB) {
            float v = 0.0f;
#pragma unroll
            for (int j = 0; j < TB; ++j)
                if (sl == j) v = r[j];
            Out[(size_t)(b0 + sl) * O_SZ + (obase + oi * 8)] = v;
        }
    }
}

extern "C" void kernel_launch(void* const* d_in, const int* in_sizes, int n_in,
                              void* d_out, int out_size, void* d_ws, size_t ws_size,
                              hipStream_t stream) {
    const float* x = (const float*)d_in[0];   // (B, I)
    const float* w = (const float*)d_in[1];   // (O, I)
    const float* s = (const float*)d_in[2];   // (O, I)
    const float* t = (const float*)d_in[3];   // (O, I)
    float* out = (float*)d_out;               // (B, O)

    dim3 grid(O_SZ / (8 * OITER), B_SZ / TB); // (32, 64) = 2048 blocks = 8/CU resident
    wavkan_dog_kernel<<<grid, 256, 0, stream>>>(x, w, s, t, out);
}